// Round 14
// baseline (97.691 us; speedup 1.0000x reference)
//
#include <hip/hip_runtime.h>

// RGCN block-decomposition: two-level counting sort (bucket, then (tl,r)
// within bucket) + sum-before-multiply grid-stride consumer, ILP=8.
//
// Evidence: atomic path ~115us (R1/5/6/7); fat ILP=8 falsified (R11);
// LDS-fused consumer falsified (R12); sum-before-multiply consumer = 55us
// at 54% occupancy (R13). This round: (a) consumer becomes grid-stride over
// 32-edge chunks at an exactly-resident 1024-block grid (occupancy fix);
// (b) sort prefix machinery slimmed to ghist + 1-block scan + atomic range
// reservation (R12's proven scatter), dropping one dispatch.
//
//   1. histG:   per-tile LDS histogram -> atomicAdd into ghist[nb]
//   2. scan1:   1-block exclusive scan -> bbase[nb+1], seeds gcur
//   3. scatterG: per-tile LDS hist -> one gcur reservation per bucket ->
//                LDS-cursor scatter of {w | tl|r|s} u64 into bucket order
//   4. sortW:   per-bucket 512-counter sort by (tl<<3)|r in LDS
//   5. rgcn_chunk_kernel: grid-stride waves over 32-edge chunks, slim ILP=8,
//      per-lane agg, 8x8 transform only at (t,r) segment boundaries

#define DIM 64
#define NBLK 8
#define BS 8
#define NREL 8
#define COL_PAD 12                                  // 8 -> 12 floats row pad
#define LDS_T_TOTAL (NREL * NBLK * BS * COL_PAD)    // 6144 floats = 24 KiB
#define CHUNK 32

#define TILE 4096      // edges per sort tile
#define MAXB 1024      // max buckets (LDS hist/cursor arrays)
#define SORTW_CAP 4096 // max edges staged per bucket in sortW (32 KiB)

typedef unsigned int uint32;
typedef unsigned long long uint64;
typedef unsigned short uint16;

// ---- 1. global bucket histogram (LDS-staged per tile) -----------------------
__global__ __launch_bounds__(512) void histG(
    const int* __restrict__ tgt, uint32* __restrict__ ghist,
    int num_edges, int nb)
{
    __shared__ uint32 h[MAXB];
    for (int i = threadIdx.x; i < nb; i += 512) h[i] = 0u;
    __syncthreads();
    const int base = blockIdx.x * TILE;
    const int end  = min(base + TILE, num_edges);
    for (int j = base + (int)threadIdx.x; j < end; j += 512)
        atomicAdd(&h[tgt[j] >> 6], 1u);
    __syncthreads();
    for (int i = threadIdx.x; i < nb; i += 512)
        if (h[i]) atomicAdd(&ghist[i], h[i]);
}

// ---- 2. exclusive scan -> bbase[0..nb]; seed gcur = bbase -------------------
__global__ __launch_bounds__(512) void scan1(
    const uint32* __restrict__ ghist, uint32* __restrict__ bbase,
    uint32* __restrict__ gcur, int nb)
{
    __shared__ uint32 wtot[8];
    const int tid = threadIdx.x, lane = tid & 63, wid = tid >> 6;
    uint32 carry = 0;
    const int nch = (nb + 511) >> 9;
    for (int c = 0; c < nch; ++c) {
        const int idx = (c << 9) + tid;
        uint32 v = (idx < nb) ? ghist[idx] : 0u;
        uint32 xin = v;
#pragma unroll
        for (int d = 1; d < 64; d <<= 1) {
            uint32 t = __shfl_up(xin, d, 64);
            if (lane >= d) xin += t;
        }
        if (lane == 63) wtot[wid] = xin;
        __syncthreads();
        if (wid == 0) {
            uint32 y = (lane < 8) ? wtot[lane] : 0u;
#pragma unroll
            for (int d = 1; d < 8; d <<= 1) {
                uint32 t = __shfl_up(y, d, 64);
                if (lane >= d) y += t;
            }
            if (lane < 8) wtot[lane] = y;
        }
        __syncthreads();
        const uint32 base = carry + ((wid > 0) ? wtot[wid - 1] : 0u);
        if (idx < nb) {
            const uint32 e = base + xin - v;
            bbase[idx] = e;
            gcur[idx]  = e;
        }
        carry += wtot[7];
        __syncthreads();
    }
    if (tid == 0) bbase[nb] = carry;
}

// ---- 3. scatter into bucket regions (unstable order; re-sorted in sortW) ----
__global__ __launch_bounds__(512) void scatterG(
    const int* __restrict__ src, const int* __restrict__ tgt,
    const int* __restrict__ etype, const float* __restrict__ ew,
    uint32* __restrict__ gcur, uint64* __restrict__ payload,
    int num_edges, int nb)
{
    __shared__ uint32 h[MAXB];
    __shared__ uint32 cur[MAXB];
    for (int i = threadIdx.x; i < nb; i += 512) h[i] = 0u;
    __syncthreads();
    const int base = blockIdx.x * TILE;
    const int end  = min(base + TILE, num_edges);
    for (int j = base + (int)threadIdx.x; j < end; j += 512)
        atomicAdd(&h[tgt[j] >> 6], 1u);
    __syncthreads();
    for (int i = threadIdx.x; i < nb; i += 512)
        if (h[i]) cur[i] = atomicAdd(&gcur[i], h[i]);   // reserve range
    __syncthreads();
    for (int j = base + (int)threadIdx.x; j < end; j += 512) {
        const int t = tgt[j];
        const uint32 pos = atomicAdd(&cur[t >> 6], 1u);
        // lo: s[0:15] | r[16:18] | tlocal[19:24]  (s < 65536, r < 8)
        const uint32 lo = (uint32)src[j] | ((uint32)etype[j] << 16)
                        | ((uint32)(t & 63) << 19);
        payload[pos] = ((uint64)__float_as_uint(ew[j]) << 32) | lo;
    }
}

// ---- 4. within-bucket counting sort by (tl<<3)|r (in place, LDS-staged) -----
__global__ __launch_bounds__(512) void sortW(
    uint64* __restrict__ payload, uint16* __restrict__ keyt,
    const uint32* __restrict__ bbase)
{
    __shared__ uint64 pay[SORTW_CAP];     // 32 KiB
    __shared__ uint32 hist[512];
    __shared__ uint32 cur[512];
    __shared__ uint32 wtot[8];
    const int tid = threadIdx.x;
    const int b   = blockIdx.x;
    const int beg = (int)bbase[b];
    const int cnt = (int)bbase[b + 1] - beg;

    if (cnt > SORTW_CAP) {   // oversized bucket: skip sort, just fill keys.
        for (int k = tid; k < cnt; k += 512) {
            const uint32 lo = (uint32)payload[beg + k];
            keyt[beg + k] = (uint16)((b << 6) | ((lo >> 19) & 63u));
        }
        return;              // consumer stays correct (more XFORMs only)
    }

    for (int k = tid; k < cnt; k += 512) pay[k] = payload[beg + k];
    hist[tid] = 0u;
    __syncthreads();
    // key = bits 16..24 of lo = (tl<<3) | r  -> tl-major, r-minor order
    for (int k = tid; k < cnt; k += 512)
        atomicAdd(&hist[((uint32)pay[k] >> 16) & 511u], 1u);
    __syncthreads();
    {   // block-wide exclusive scan of the 512 counters
        const int lane = tid & 63, wid = tid >> 6;
        uint32 v = hist[tid], xin = v;
#pragma unroll
        for (int d = 1; d < 64; d <<= 1) {
            uint32 t = __shfl_up(xin, d, 64);
            if (lane >= d) xin += t;
        }
        if (lane == 63) wtot[wid] = xin;
        __syncthreads();
        if (wid == 0) {
            uint32 y = (lane < 8) ? wtot[lane] : 0u;
#pragma unroll
            for (int d = 1; d < 8; d <<= 1) {
                uint32 t = __shfl_up(y, d, 64);
                if (lane >= d) y += t;
            }
            if (lane < 8) wtot[lane] = y;
        }
        __syncthreads();
        cur[tid] = ((wid > 0) ? wtot[wid - 1] : 0u) + xin - v;
    }
    __syncthreads();
    for (int k = tid; k < cnt; k += 512) {
        const uint64 p   = pay[k];
        const uint32 key = ((uint32)p >> 16) & 511u;
        const uint32 pos = atomicAdd(&cur[key], 1u);
        payload[beg + pos] = p;
        keyt[beg + pos] = (uint16)((b << 6) | (key >> 3));
    }
}

// ---- 5. sum-before-multiply grid-stride consumer, ILP=8 slim slots ----------
// Per edge: 1 dword of x per lane + 1 fma into agg[lane]. Transform applied
// at (t,r) segment boundary: out_ch(lane) += sum_i B[r][bq][i][oo]*agg[bq*8+i]
// via 8 shfl + 8 fma + 2 ds_read_b128.
#define XFORM(r_)                                                           \
    {                                                                       \
        const float* bp = bcol + (int)(r_) * (NBLK * BS * COL_PAD);         \
        const float4 c0 = *(const float4*)bp;                               \
        const float4 c1 = *(const float4*)(bp + 4);                         \
        const int bl = lane & ~7;                                           \
        oacc += c0.x * __shfl(agg, bl + 0, 64)                              \
              + c0.y * __shfl(agg, bl + 1, 64)                              \
              + c0.z * __shfl(agg, bl + 2, 64)                              \
              + c0.w * __shfl(agg, bl + 3, 64)                              \
              + c1.x * __shfl(agg, bl + 4, 64)                              \
              + c1.y * __shfl(agg, bl + 5, 64)                              \
              + c1.z * __shfl(agg, bl + 6, 64)                              \
              + c1.w * __shfl(agg, bl + 7, 64);                             \
        agg = 0.0f;                                                         \
    }

#define PREQ(i, lov, wv)                                                    \
    const uint32 lo##i = (lov);                                             \
    const float  w##i  = __uint_as_float(wv);                               \
    const float  xv##i = x[((size_t)(lo##i & 0xFFFFu) << 6) + lane];

#define ACC(i, t_)                                                          \
    {                                                                       \
        const int    tt = (int)(t_);                                        \
        const uint32 rr = (lo##i >> 16) & 7u;                               \
        if (tt != tcur || rr != rcur) {                                     \
            XFORM(rcur)                                                     \
            if (tt != tcur) {                                               \
                atomicAdd(out + (size_t)tcur * DIM + lane, oacc);           \
                oacc = 0.0f; tcur = tt;                                     \
            }                                                               \
            rcur = rr;                                                      \
        }                                                                   \
        agg = fmaf(w##i, xv##i, agg);                                       \
    }

__global__ __launch_bounds__(512) void rgcn_chunk_kernel(
    const float* __restrict__ x,
    const float* __restrict__ blocks,
    const uint64* __restrict__ payload,
    const uint16* __restrict__ keyt,
    float* __restrict__ out,
    int num_edges)
{
    __shared__ float blkT[LDS_T_TOTAL];
    // blkT[((r*8+b)*8 + o)*12 + i] = blocks[r][b][i][o]; per-lane column read
    // is 2x ds_read_b128 at 48B stride -> 2 lanes/bank (0 conflicts measured).
    for (int l = threadIdx.x; l < NREL * NBLK * BS * BS; l += blockDim.x) {
        const int o = l & 7;
        const int i = (l >> 3) & 7;
        const int rb = l >> 6;
        blkT[(rb * 8 + o) * COL_PAD + i] = blocks[l];
    }
    __syncthreads();

    const int lane = threadIdx.x & 63;
    const int wid  = __builtin_amdgcn_readfirstlane(threadIdx.x >> 6);
    const int wave = blockIdx.x * 8 + wid;             // blockDim == 512
    const int W    = gridDim.x * 8;                    // total waves

    const int bq = lane >> 3;   // which 8x8 block
    const int oo = lane & 7;    // output channel within block
    const float* bcol = &blkT[(bq * 8 + oo) * COL_PAD];

    const int nch = (num_edges + CHUNK - 1) / CHUNK;
    for (int c = wave; c < nch; c += W) {
        const int beg = c * CHUNK;
        const int end = min(beg + CHUNK, num_edges);

        int    tcur = (int)keyt[beg];
        uint32 rcur = ((uint32)payload[beg] >> 16) & 7u;
        float  agg  = 0.0f;   // per-lane input-channel segment sum
        float  oacc = 0.0f;   // per-lane output accumulator for tcur

        int j = beg;
        // 8 edges in flight: 4x uint4 payload + 2x ushort4 key + 8x dword x.
        for (; j + 8 <= end; j += 8) {
            const uint4 q0 = *(const uint4*)(payload + j);    // lo0,w0,lo1,w1
            const uint4 q1 = *(const uint4*)(payload + j + 2);
            const uint4 q2 = *(const uint4*)(payload + j + 4);
            const uint4 q3 = *(const uint4*)(payload + j + 6);
            const ushort4 ka = *(const ushort4*)(keyt + j);   // beg%4==0
            const ushort4 kb = *(const ushort4*)(keyt + j + 4);
            PREQ(0, q0.x, q0.y) PREQ(1, q0.z, q0.w)
            PREQ(2, q1.x, q1.y) PREQ(3, q1.z, q1.w)
            PREQ(4, q2.x, q2.y) PREQ(5, q2.z, q2.w)
            PREQ(6, q3.x, q3.y) PREQ(7, q3.z, q3.w)
            ACC(0, ka.x) ACC(1, ka.y) ACC(2, ka.z) ACC(3, ka.w)
            ACC(4, kb.x) ACC(5, kb.y) ACC(6, kb.z) ACC(7, kb.w)
        }
        for (; j < end; ++j) {                                // tail
            const uint64 p0 = payload[j];
            const uint16 k0 = keyt[j];
            PREQ(0, (uint32)p0, (uint32)(p0 >> 32))
            ACC(0, k0)
        }
        XFORM(rcur)                                           // final segment
        atomicAdd(out + (size_t)tcur * DIM + lane, oacc);     // final flush
    }
}

// ---- Fallback (ws too small / nb too big): round-1 proven atomic kernel -----
#define LDS_BLK_STRIDE 72
#define LDS_REL_STRIDE (NBLK * LDS_BLK_STRIDE)
#define LDS_TOTAL (NREL * LDS_REL_STRIDE)

__global__ __launch_bounds__(256) void rgcn_edge_kernel(
    const float* __restrict__ x, const float* __restrict__ blocks,
    const float* __restrict__ ew, const int* __restrict__ src,
    const int* __restrict__ tgt, const int* __restrict__ etype,
    float* __restrict__ out, int num_edges)
{
    __shared__ float blk[LDS_TOTAL];
    for (int l = threadIdx.x; l < NREL * NBLK * BS * BS; l += blockDim.x) {
        int r = l >> 9, bb = (l >> 6) & 7, rest = l & 63;
        blk[r * LDS_REL_STRIDE + bb * LDS_BLK_STRIDE + rest] = blocks[l];
    }
    __syncthreads();
    const int lane = threadIdx.x & 63;
    const int wave = blockIdx.x * (blockDim.x >> 6) + (threadIdx.x >> 6);
    const int total_waves = gridDim.x * (blockDim.x >> 6);
    const int b = lane >> 3;
    for (int e = wave; e < num_edges; e += total_waves) {
        const int s = src[e], t = tgt[e], r = etype[e];
        const float w = ew[e];
        const float4* xs = reinterpret_cast<const float4*>(x + (size_t)s * DIM + b * BS);
        const float4 v0 = xs[0], v1 = xs[1];
        const float* bb = &blk[r * LDS_REL_STRIDE + b * LDS_BLK_STRIDE + (lane & 7)];
        float a = v0.x * bb[0] + v0.y * bb[BS] + v0.z * bb[2 * BS] + v0.w * bb[3 * BS]
                + v1.x * bb[4 * BS] + v1.y * bb[5 * BS] + v1.z * bb[6 * BS] + v1.w * bb[7 * BS];
        atomicAdd(&out[(size_t)t * DIM + lane], w * a);
    }
}

extern "C" void kernel_launch(void* const* d_in, const int* in_sizes, int n_in,
                              void* d_out, int out_size, void* d_ws, size_t ws_size,
                              hipStream_t stream) {
    const float* x      = (const float*)d_in[0];
    const float* blocks = (const float*)d_in[1];
    const float* ew     = (const float*)d_in[2];
    const int*   src    = (const int*)d_in[3];
    const int*   tgt    = (const int*)d_in[4];
    const int*   etype  = (const int*)d_in[5];
    float* out = (float*)d_out;

    const int num_edges = in_sizes[2];
    const int num_nodes = in_sizes[0] / DIM;

    const int nb = (num_nodes + 63) >> 6;           // 64-node buckets
    const int nt = (num_edges + TILE - 1) / TILE;   // sort tiles

    // ws: payload (E u64) | keyt (E u16) | ghist (nb) | bbase (nb+1) | gcur (nb)
    const size_t payload_b = (size_t)num_edges * 8;
    const size_t keyt_b    = (size_t)num_edges * 2;
    const size_t gh_b      = (size_t)nb * 4;
    const size_t bb_b      = (size_t)(nb + 1) * 4;
    const size_t gc_b      = (size_t)nb * 4;
    const size_t need      = payload_b + keyt_b + gh_b + bb_b + gc_b;

    if (nb > MAXB || ws_size < need) {   // fallback: round-1 atomic kernel
        hipMemsetAsync(d_out, 0, (size_t)out_size * sizeof(float), stream);
        rgcn_edge_kernel<<<2048, 256, 0, stream>>>(
            x, blocks, ew, src, tgt, etype, out, num_edges);
        return;
    }

    char* ws = (char*)d_ws;
    uint64* payload = (uint64*)ws;
    uint16* keyt    = (uint16*)(ws + payload_b);
    uint32* ghist   = (uint32*)(ws + payload_b + keyt_b);
    uint32* bbase   = (uint32*)(ws + payload_b + keyt_b + gh_b);
    uint32* gcur    = (uint32*)(ws + payload_b + keyt_b + gh_b + bb_b);

    hipMemsetAsync(ghist, 0, gh_b, stream);
    hipMemsetAsync(d_out, 0, (size_t)out_size * sizeof(float), stream);
    histG<<<nt, 512, 0, stream>>>(tgt, ghist, num_edges, nb);
    scan1<<<1, 512, 0, stream>>>(ghist, bbase, gcur, nb);
    scatterG<<<nt, 512, 0, stream>>>(
        src, tgt, etype, ew, gcur, payload, num_edges, nb);
    sortW<<<nb, 512, 0, stream>>>(payload, keyt, bbase);

    const int nchunks = (num_edges + CHUNK - 1) / CHUNK;
    const int gblocks = min((nchunks + 7) / 8, 1024);   // exactly-resident grid
    rgcn_chunk_kernel<<<gblocks, 512, 0, stream>>>(
        x, blocks, payload, keyt, out, num_edges);
}

// Round 15
// 89.161 us; speedup vs baseline: 1.0957x; 1.0957x over previous
//
#include <hip/hip_runtime.h>

// RGCN block-decomposition: two-level counting sort (bucket, then (tl,r)
// within bucket) + sum-before-multiply consumer, ILP=8, CHUNK=64.
//
// R14 falsified the occupancy theory (grid-stride @1024: occ unchanged 56%,
// consumer unchanged 55us -> consumer is pinned by random x-row fetch, not
// wave slots) and the slim sort (43us > R13's 36us). This round: exact R13
// revert + keyt[] eliminated by packing the bucket id into 10 stolen
// mantissa bits of w (hi = (w_bits & ~1023) | bucket; rel err 2^-13,
// negligible vs 0.315 threshold).
//
//   1. histA:       per-4096-edge tile histogram of bucket = tgt>>6
//   2. colscan:     per-bucket exclusive prefix over tiles + totals
//   3. scan_totals: exclusive scan of bucket totals -> bbase[nb+1]
//   4. scatterB:    LDS-cursor scatter of {w|bkt || tl|r|s} u64, bucket order
//   5. sortW:       per-bucket 512-counter sort by (tl<<3)|r in LDS
//   6. rgcn_chunk_kernel: wave per 64-edge chunk, slim ILP=8, per-lane agg,
//      8x8 transform only at (t,r) segment boundaries. No keyt array.

#define DIM 64
#define NBLK 8
#define BS 8
#define NREL 8
#define COL_PAD 12                                  // 8 -> 12 floats row pad
#define LDS_T_TOTAL (NREL * NBLK * BS * COL_PAD)    // 6144 floats = 24 KiB
#define CHUNK 64

#define TILE 4096      // edges per sort tile
#define MAXB 1024      // max buckets (10-bit bucket id in payload hi)
#define SORTW_CAP 4096 // max edges staged per bucket in sortW (32 KiB)

typedef unsigned int uint32;
typedef unsigned long long uint64;

// ---- 1. per-tile bucket histogram -------------------------------------------
__global__ __launch_bounds__(512) void histA(
    const int* __restrict__ tgt, uint32* __restrict__ tile_hist,
    int num_edges, int nb)
{
    __shared__ uint32 h[MAXB];
    for (int i = threadIdx.x; i < nb; i += 512) h[i] = 0u;
    __syncthreads();
    const int base = blockIdx.x * TILE;
    const int end  = min(base + TILE, num_edges);
    for (int j = base + (int)threadIdx.x; j < end; j += 512)
        atomicAdd(&h[tgt[j] >> 6], 1u);
    __syncthreads();
    uint32* dst = tile_hist + (size_t)blockIdx.x * nb;
    for (int i = threadIdx.x; i < nb; i += 512) dst[i] = h[i];
}

// ---- 2. per-bucket exclusive prefix over tiles (in place) + totals ----------
__global__ __launch_bounds__(64) void colscan(
    uint32* __restrict__ tile_hist, uint32* __restrict__ totals,
    int nt, int nb)
{
    const int b    = blockIdx.x;
    const int lane = threadIdx.x;
    uint32 carry = 0;
    for (int t0 = 0; t0 < nt; t0 += 64) {
        const int t = t0 + lane;
        uint32 v = (t < nt) ? tile_hist[(size_t)t * nb + b] : 0u;
        uint32 xin = v;
#pragma unroll
        for (int d = 1; d < 64; d <<= 1) {
            uint32 tm = __shfl_up(xin, d, 64);
            if (lane >= d) xin += tm;
        }
        if (t < nt) tile_hist[(size_t)t * nb + b] = carry + xin - v;
        carry += __shfl(xin, 63, 64);
    }
    if (lane == 0) totals[b] = carry;
}

// ---- 3. exclusive scan of bucket totals -> bbase[0..nb] ---------------------
__global__ __launch_bounds__(512) void scan_totals(
    const uint32* __restrict__ totals, uint32* __restrict__ bbase, int nb)
{
    __shared__ uint32 wtot[8];
    const int tid = threadIdx.x, lane = tid & 63, wid = tid >> 6;
    uint32 carry = 0;
    const int nch = (nb + 511) >> 9;
    for (int c = 0; c < nch; ++c) {
        const int idx = (c << 9) + tid;
        uint32 v = (idx < nb) ? totals[idx] : 0u;
        uint32 xin = v;
#pragma unroll
        for (int d = 1; d < 64; d <<= 1) {
            uint32 t = __shfl_up(xin, d, 64);
            if (lane >= d) xin += t;
        }
        if (lane == 63) wtot[wid] = xin;
        __syncthreads();
        if (wid == 0) {
            uint32 y = (lane < 8) ? wtot[lane] : 0u;
#pragma unroll
            for (int d = 1; d < 8; d <<= 1) {
                uint32 t = __shfl_up(y, d, 64);
                if (lane >= d) y += t;
            }
            if (lane < 8) wtot[lane] = y;
        }
        __syncthreads();
        const uint32 base = carry + ((wid > 0) ? wtot[wid - 1] : 0u);
        if (idx < nb) bbase[idx] = base + xin - v;
        carry += wtot[7];
        __syncthreads();
    }
    if (tid == 0) bbase[nb] = carry;
}

// ---- 4. scatter packed payloads into bucket-sorted order --------------------
__global__ __launch_bounds__(512) void scatterB(
    const int* __restrict__ src, const int* __restrict__ tgt,
    const int* __restrict__ etype, const float* __restrict__ ew,
    const uint32* __restrict__ tile_hist, const uint32* __restrict__ bbase,
    uint64* __restrict__ payload, int num_edges, int nb)
{
    __shared__ uint32 cur[MAXB];
    const uint32* th = tile_hist + (size_t)blockIdx.x * nb;
    for (int i = threadIdx.x; i < nb; i += 512) cur[i] = bbase[i] + th[i];
    __syncthreads();
    const int base = blockIdx.x * TILE;
    const int end  = min(base + TILE, num_edges);
    for (int j = base + (int)threadIdx.x; j < end; j += 512) {
        const int t = tgt[j];
        const uint32 pos = atomicAdd(&cur[t >> 6], 1u);
        // lo: s[0:15] | r[16:18] | tl[19:24];  hi: w_mantissa-trimmed | bucket
        const uint32 lo = (uint32)src[j] | ((uint32)etype[j] << 16)
                        | ((uint32)(t & 63) << 19);
        const uint32 hi = (__float_as_uint(ew[j]) & ~1023u)
                        | (uint32)(t >> 6);
        payload[pos] = ((uint64)hi << 32) | lo;
    }
}

// ---- 5. within-bucket counting sort by (tl<<3)|r (in place, LDS-staged) -----
__global__ __launch_bounds__(512) void sortW(
    uint64* __restrict__ payload, const uint32* __restrict__ bbase)
{
    __shared__ uint64 pay[SORTW_CAP];     // 32 KiB
    __shared__ uint32 hist[512];
    __shared__ uint32 cur[512];
    __shared__ uint32 wtot[8];
    const int tid = threadIdx.x;
    const int b   = blockIdx.x;
    const int beg = (int)bbase[b];
    const int cnt = (int)bbase[b + 1] - beg;

    if (cnt > SORTW_CAP) return;   // oversized: unsorted order is still
                                   // correct (consumer just XFORMs more)

    for (int k = tid; k < cnt; k += 512) pay[k] = payload[beg + k];
    hist[tid] = 0u;
    __syncthreads();
    // key = bits 16..24 of lo = (tl<<3) | r  -> tl-major, r-minor order
    for (int k = tid; k < cnt; k += 512)
        atomicAdd(&hist[((uint32)pay[k] >> 16) & 511u], 1u);
    __syncthreads();
    {   // block-wide exclusive scan of the 512 counters
        const int lane = tid & 63, wid = tid >> 6;
        uint32 v = hist[tid], xin = v;
#pragma unroll
        for (int d = 1; d < 64; d <<= 1) {
            uint32 t = __shfl_up(xin, d, 64);
            if (lane >= d) xin += t;
        }
        if (lane == 63) wtot[wid] = xin;
        __syncthreads();
        if (wid == 0) {
            uint32 y = (lane < 8) ? wtot[lane] : 0u;
#pragma unroll
            for (int d = 1; d < 8; d <<= 1) {
                uint32 t = __shfl_up(y, d, 64);
                if (lane >= d) y += t;
            }
            if (lane < 8) wtot[lane] = y;
        }
        __syncthreads();
        cur[tid] = ((wid > 0) ? wtot[wid - 1] : 0u) + xin - v;
    }
    __syncthreads();
    for (int k = tid; k < cnt; k += 512) {
        const uint64 p   = pay[k];
        const uint32 key = ((uint32)p >> 16) & 511u;
        payload[beg + atomicAdd(&cur[key], 1u)] = p;
    }
}

// ---- 6. sum-before-multiply consumer, ILP=8 slim slots, no keyt -------------
// Per edge: 1 dword of x per lane + 1 fma into agg[lane]. Transform applied
// at (t,r) segment boundary: out_ch(lane) += sum_i B[r][bq][i][oo]*agg[bq*8+i]
// via 8 shfl + 8 fma + 2 ds_read_b128. Target id from payload:
// t = (hi&1023)<<6 | (lo>>19)&63;  w = as_float(hi & ~1023).
#define XFORM(r_)                                                           \
    {                                                                       \
        const float* bp = bcol + (int)(r_) * (NBLK * BS * COL_PAD);         \
        const float4 c0 = *(const float4*)bp;                               \
        const float4 c1 = *(const float4*)(bp + 4);                         \
        const int bl = lane & ~7;                                           \
        oacc += c0.x * __shfl(agg, bl + 0, 64)                              \
              + c0.y * __shfl(agg, bl + 1, 64)                              \
              + c0.z * __shfl(agg, bl + 2, 64)                              \
              + c0.w * __shfl(agg, bl + 3, 64)                              \
              + c1.x * __shfl(agg, bl + 4, 64)                              \
              + c1.y * __shfl(agg, bl + 5, 64)                              \
              + c1.z * __shfl(agg, bl + 6, 64)                              \
              + c1.w * __shfl(agg, bl + 7, 64);                             \
        agg = 0.0f;                                                         \
    }

#define PREQ(i, lov, hiv)                                                   \
    const uint32 lo##i = (lov);                                             \
    const uint32 hi##i = (hiv);                                             \
    const float  w##i  = __uint_as_float(hi##i & ~1023u);                   \
    const float  xv##i = x[((size_t)(lo##i & 0xFFFFu) << 6) + lane];

#define ACC(i)                                                              \
    {                                                                       \
        const int    tt = (int)(((hi##i & 1023u) << 6) |                    \
                                ((lo##i >> 19) & 63u));                     \
        const uint32 rr = (lo##i >> 16) & 7u;                               \
        if (tt != tcur || rr != rcur) {                                     \
            XFORM(rcur)                                                     \
            if (tt != tcur) {                                               \
                atomicAdd(out + (size_t)tcur * DIM + lane, oacc);           \
                oacc = 0.0f; tcur = tt;                                     \
            }                                                               \
            rcur = rr;                                                      \
        }                                                                   \
        agg = fmaf(w##i, xv##i, agg);                                       \
    }

__global__ __launch_bounds__(512) void rgcn_chunk_kernel(
    const float* __restrict__ x,
    const float* __restrict__ blocks,
    const uint64* __restrict__ payload,
    float* __restrict__ out,
    int num_edges)
{
    __shared__ float blkT[LDS_T_TOTAL];
    // blkT[((r*8+b)*8 + o)*12 + i] = blocks[r][b][i][o]; per-lane column read
    // is 2x ds_read_b128 at 48B stride -> 2 lanes/bank (0 conflicts measured).
    for (int l = threadIdx.x; l < NREL * NBLK * BS * BS; l += blockDim.x) {
        const int o = l & 7;
        const int i = (l >> 3) & 7;
        const int rb = l >> 6;
        blkT[(rb * 8 + o) * COL_PAD + i] = blocks[l];
    }
    __syncthreads();

    const int lane = threadIdx.x & 63;
    const int wid  = __builtin_amdgcn_readfirstlane(threadIdx.x >> 6);
    const int wave = blockIdx.x * (int)(blockDim.x >> 6) + wid;
    const int beg  = wave * CHUNK;
    if (beg >= num_edges) return;
    const int end  = min(beg + CHUNK, num_edges);

    const int bq = lane >> 3;   // which 8x8 block
    const int oo = lane & 7;    // output channel within block
    const float* bcol = &blkT[(bq * 8 + oo) * COL_PAD];

    {
        const uint64 p  = payload[beg];
        const uint32 l0 = (uint32)p;
        const uint32 h0 = (uint32)(p >> 32);
        int    tcur = (int)(((h0 & 1023u) << 6) | ((l0 >> 19) & 63u));
        uint32 rcur = (l0 >> 16) & 7u;
        float  agg  = 0.0f;   // per-lane input-channel segment sum
        float  oacc = 0.0f;   // per-lane output accumulator for tcur

        int j = beg;
        // 8 edges in flight: 4x uint4 payload + 8x dword x.
        for (; j + 8 <= end; j += 8) {
            const uint4 q0 = *(const uint4*)(payload + j);    // lo0,hi0,lo1,hi1
            const uint4 q1 = *(const uint4*)(payload + j + 2);
            const uint4 q2 = *(const uint4*)(payload + j + 4);
            const uint4 q3 = *(const uint4*)(payload + j + 6);
            PREQ(0, q0.x, q0.y) PREQ(1, q0.z, q0.w)
            PREQ(2, q1.x, q1.y) PREQ(3, q1.z, q1.w)
            PREQ(4, q2.x, q2.y) PREQ(5, q2.z, q2.w)
            PREQ(6, q3.x, q3.y) PREQ(7, q3.z, q3.w)
            ACC(0) ACC(1) ACC(2) ACC(3)
            ACC(4) ACC(5) ACC(6) ACC(7)
        }
        for (; j < end; ++j) {                                // tail
            const uint64 p0 = payload[j];
            PREQ(0, (uint32)p0, (uint32)(p0 >> 32))
            ACC(0)
        }
        XFORM(rcur)                                           // final segment
        atomicAdd(out + (size_t)tcur * DIM + lane, oacc);     // final flush
    }
}

// ---- Fallback (ws too small / nb too big): round-1 proven atomic kernel -----
#define LDS_BLK_STRIDE 72
#define LDS_REL_STRIDE (NBLK * LDS_BLK_STRIDE)
#define LDS_TOTAL (NREL * LDS_REL_STRIDE)

__global__ __launch_bounds__(256) void rgcn_edge_kernel(
    const float* __restrict__ x, const float* __restrict__ blocks,
    const float* __restrict__ ew, const int* __restrict__ src,
    const int* __restrict__ tgt, const int* __restrict__ etype,
    float* __restrict__ out, int num_edges)
{
    __shared__ float blk[LDS_TOTAL];
    for (int l = threadIdx.x; l < NREL * NBLK * BS * BS; l += blockDim.x) {
        int r = l >> 9, bb = (l >> 6) & 7, rest = l & 63;
        blk[r * LDS_REL_STRIDE + bb * LDS_BLK_STRIDE + rest] = blocks[l];
    }
    __syncthreads();
    const int lane = threadIdx.x & 63;
    const int wave = blockIdx.x * (blockDim.x >> 6) + (threadIdx.x >> 6);
    const int total_waves = gridDim.x * (blockDim.x >> 6);
    const int b = lane >> 3;
    for (int e = wave; e < num_edges; e += total_waves) {
        const int s = src[e], t = tgt[e], r = etype[e];
        const float w = ew[e];
        const float4* xs = reinterpret_cast<const float4*>(x + (size_t)s * DIM + b * BS);
        const float4 v0 = xs[0], v1 = xs[1];
        const float* bb = &blk[r * LDS_REL_STRIDE + b * LDS_BLK_STRIDE + (lane & 7)];
        float a = v0.x * bb[0] + v0.y * bb[BS] + v0.z * bb[2 * BS] + v0.w * bb[3 * BS]
                + v1.x * bb[4 * BS] + v1.y * bb[5 * BS] + v1.z * bb[6 * BS] + v1.w * bb[7 * BS];
        atomicAdd(&out[(size_t)t * DIM + lane], w * a);
    }
}

extern "C" void kernel_launch(void* const* d_in, const int* in_sizes, int n_in,
                              void* d_out, int out_size, void* d_ws, size_t ws_size,
                              hipStream_t stream) {
    const float* x      = (const float*)d_in[0];
    const float* blocks = (const float*)d_in[1];
    const float* ew     = (const float*)d_in[2];
    const int*   src    = (const int*)d_in[3];
    const int*   tgt    = (const int*)d_in[4];
    const int*   etype  = (const int*)d_in[5];
    float* out = (float*)d_out;

    const int num_edges = in_sizes[2];
    const int num_nodes = in_sizes[0] / DIM;

    const int nb = (num_nodes + 63) >> 6;           // 64-node buckets
    const int nt = (num_edges + TILE - 1) / TILE;   // sort tiles

    // ws: payload (E u64) | tile_hist (nt*nb u32) | totals (nb) | bbase (nb+1)
    const size_t payload_b = (size_t)num_edges * 8;
    const size_t th_b      = (size_t)nt * nb * 4;
    const size_t tot_b     = (size_t)nb * 4;
    const size_t bb_b      = (size_t)(nb + 1) * 4;
    const size_t need      = payload_b + th_b + tot_b + bb_b;

    if (nb > MAXB || ws_size < need) {   // fallback: round-1 atomic kernel
        hipMemsetAsync(d_out, 0, (size_t)out_size * sizeof(float), stream);
        rgcn_edge_kernel<<<2048, 256, 0, stream>>>(
            x, blocks, ew, src, tgt, etype, out, num_edges);
        return;
    }

    char* ws = (char*)d_ws;
    uint64* payload   = (uint64*)ws;
    uint32* tile_hist = (uint32*)(ws + payload_b);
    uint32* totals    = (uint32*)(ws + payload_b + th_b);
    uint32* bbase     = (uint32*)(ws + payload_b + th_b + tot_b);

    hipMemsetAsync(d_out, 0, (size_t)out_size * sizeof(float), stream);
    histA<<<nt, 512, 0, stream>>>(tgt, tile_hist, num_edges, nb);
    colscan<<<nb, 64, 0, stream>>>(tile_hist, totals, nt, nb);
    scan_totals<<<1, 512, 0, stream>>>(totals, bbase, nb);
    scatterB<<<nt, 512, 0, stream>>>(
        src, tgt, etype, ew, tile_hist, bbase, payload, num_edges, nb);
    sortW<<<nb, 512, 0, stream>>>(payload, bbase);

    const int waves   = (num_edges + CHUNK - 1) / CHUNK;
    const int gblocks = (waves + 7) / 8;
    rgcn_chunk_kernel<<<gblocks, 512, 0, stream>>>(
        x, blocks, payload, out, num_edges);
}